// Round 1
// baseline (4335.852 us; speedup 1.0000x reference)
//
#include <hip/hip_runtime.h>

#define N_IN 64
#define HID 128
#define OUT_F 64

// ---------------------------------------------------------------------------
// degree: deg[dst[e]] += 1
// ---------------------------------------------------------------------------
__global__ __launch_bounds__(256)
void deg_kernel(const int* __restrict__ dst, float* __restrict__ deg, int E) {
    int e = blockIdx.x * 256 + threadIdx.x;
    if (e < E) unsafeAtomicAdd(&deg[dst[e]], 1.0f);
}

// ---------------------------------------------------------------------------
// scatter-add: agg[dst[e]][:] += x[src[e]][:]
// one thread per (edge, 4-float chunk); 16-lane groups gather a contiguous
// 256B row segment (coalesced), then 4 hardware fp32 atomics.
// ---------------------------------------------------------------------------
template<int D>
__global__ __launch_bounds__(256)
void scatter_kernel(const float* __restrict__ x, const int* __restrict__ src,
                    const int* __restrict__ dst, float* __restrict__ agg, int E) {
    constexpr int C = D / 4;                       // float4 chunks per row
    int gid = blockIdx.x * 256 + threadIdx.x;
    int e = gid / C;
    if (e >= E) return;
    int c = gid % C;
    int s = src[e];
    int d = dst[e];
    const float4 v = *(const float4*)(x + (size_t)s * D + c * 4);
    float* a = agg + (size_t)d * D + c * 4;
    unsafeAtomicAdd(a + 0, v.x);
    unsafeAtomicAdd(a + 1, v.y);
    unsafeAtomicAdd(a + 2, v.z);
    unsafeAtomicAdd(a + 3, v.w);
}

// ---------------------------------------------------------------------------
// fused SAGE layer / MLP layer:
//   out[n][h] = act( sum_k x[n][k]*Ws[k][h]
//                  + (NEIGH ? (agg[n][k]/max(deg[n],1))*Wn[k][h] : 0) + b[h] )
// Block: 256 threads. Each thread: 4 rows x 4 cols fp32 accumulators.
// x/agg tile staged in LDS (agg pre-divided by degree); W read via L1/L2
// (shared across all blocks, <=128KB). In-place out==x or out==agg is safe:
// block stages its rows before writing them.
// ---------------------------------------------------------------------------
template<int K, int H, bool NEIGH, bool RELU>
__global__ __launch_bounds__(256)
void sage_gemm(const float* __restrict__ x, const float* __restrict__ agg,
               const float* __restrict__ deg, const float* __restrict__ Ws,
               const float* __restrict__ Wn, const float* __restrict__ bias,
               float* __restrict__ out, int nn) {
    constexpr int HG   = H / 4;          // h-groups (threads across H)
    constexpr int RGS  = 256 / HG;       // row-groups per block
    constexpr int ROWS = RGS * 4;        // rows per block (32 for H=128, 64 for H=64)

    __shared__ float xs[ROWS][K];
    __shared__ float as_[NEIGH ? ROWS : 1][NEIGH ? K : 1];

    const int tid  = threadIdx.x;
    const int row0 = blockIdx.x * ROWS;

    // ---- stage x (and agg/deg) tile into LDS ----
    constexpr int C        = K / 4;          // float4 per row
    constexpr int TOTAL_F4 = ROWS * C;
    for (int i = tid; i < TOTAL_F4; i += 256) {
        int r = i / C, c = i % C;
        int n = row0 + r;
        float4 v = make_float4(0.f, 0.f, 0.f, 0.f);
        if (n < nn) v = *(const float4*)(x + (size_t)n * K + c * 4);
        *(float4*)&xs[r][c * 4] = v;
        if constexpr (NEIGH) {
            float4 a = make_float4(0.f, 0.f, 0.f, 0.f);
            if (n < nn) {
                a = *(const float4*)(agg + (size_t)n * K + c * 4);
                float inv = 1.0f / fmaxf(deg[n], 1.0f);
                a.x *= inv; a.y *= inv; a.z *= inv; a.w *= inv;
            }
            *(float4*)&as_[r][c * 4] = a;
        }
    }
    __syncthreads();

    const int rg = tid / HG;          // 0..RGS-1
    const int h0 = (tid % HG) * 4;    // 0..H-4
    const int r0 = rg * 4;

    float acc[4][4];
#pragma unroll
    for (int r = 0; r < 4; ++r)
#pragma unroll
        for (int j = 0; j < 4; ++j) acc[r][j] = 0.f;

#pragma unroll 4
    for (int k = 0; k < K; ++k) {
        const float4 wsv = *(const float4*)(Ws + (size_t)k * H + h0);
        float4 wnv;
        if constexpr (NEIGH) wnv = *(const float4*)(Wn + (size_t)k * H + h0);
#pragma unroll
        for (int r = 0; r < 4; ++r) {
            float xv = xs[r0 + r][k];
            acc[r][0] += xv * wsv.x;
            acc[r][1] += xv * wsv.y;
            acc[r][2] += xv * wsv.z;
            acc[r][3] += xv * wsv.w;
            if constexpr (NEIGH) {
                float av = as_[r0 + r][k];
                acc[r][0] += av * wnv.x;
                acc[r][1] += av * wnv.y;
                acc[r][2] += av * wnv.z;
                acc[r][3] += av * wnv.w;
            }
        }
    }

    const float4 bv = *(const float4*)(bias + h0);
#pragma unroll
    for (int r = 0; r < 4; ++r) {
        int n = row0 + r0 + r;
        if (n < nn) {
            float4 o;
            o.x = acc[r][0] + bv.x;
            o.y = acc[r][1] + bv.y;
            o.z = acc[r][2] + bv.z;
            o.w = acc[r][3] + bv.w;
            if constexpr (RELU) {
                o.x = fmaxf(o.x, 0.f); o.y = fmaxf(o.y, 0.f);
                o.z = fmaxf(o.z, 0.f); o.w = fmaxf(o.w, 0.f);
            }
            *(float4*)(out + (size_t)n * H + h0) = o;
        }
    }
}

// ---------------------------------------------------------------------------
extern "C" void kernel_launch(void* const* d_in, const int* in_sizes, int n_in,
                              void* d_out, int out_size, void* d_ws, size_t ws_size,
                              hipStream_t stream) {
    const float* feat = (const float*)d_in[0];
    const float* Wn1  = (const float*)d_in[1];
    const float* Ws1  = (const float*)d_in[2];
    const float* b1   = (const float*)d_in[3];
    const float* Wn2  = (const float*)d_in[4];
    const float* Ws2  = (const float*)d_in[5];
    const float* b2   = (const float*)d_in[6];
    const float* Wm1  = (const float*)d_in[7];
    const float* bm1  = (const float*)d_in[8];
    const float* Wm2  = (const float*)d_in[9];
    const float* bm2  = (const float*)d_in[10];
    const int*   src  = (const int*)d_in[11];
    const int*   dst  = (const int*)d_in[12];

    const int nn = in_sizes[0] / N_IN;    // 100000
    const int E  = in_sizes[11];          // 1600000

    // workspace layout (floats):
    //   deg  [0, nn)
    //   agg1 [nn, nn + 64*nn)
    //   x1   [.., + 128*nn)
    //   buf3 [.., + 128*nn)   (agg2 -> x2 -> x3, all in-place safe)
    float* ws   = (float*)d_ws;
    float* deg  = ws;
    float* agg1 = ws + (size_t)nn;
    float* x1   = agg1 + (size_t)nn * N_IN;
    float* buf3 = x1 + (size_t)nn * HID;

    // zero deg+agg1 (contiguous) and agg2 region
    hipMemsetAsync(deg,  0, (size_t)nn * (1 + N_IN) * sizeof(float), stream);
    hipMemsetAsync(buf3, 0, (size_t)nn * HID * sizeof(float), stream);

    // degrees
    deg_kernel<<<(E + 255) / 256, 256, 0, stream>>>(dst, deg, E);

    // layer 1: agg1 = scatter(features); x1 = relu(feat@Ws1 + mean@Wn1 + b1)
    scatter_kernel<N_IN><<<(E * (N_IN / 4) + 255) / 256, 256, 0, stream>>>(
        feat, src, dst, agg1, E);
    sage_gemm<N_IN, HID, true, true><<<(nn + 31) / 32, 256, 0, stream>>>(
        feat, agg1, deg, Ws1, Wn1, b1, x1, nn);

    // layer 2: buf3 = scatter(x1); x2 = relu(x1@Ws2 + mean@Wn2 + b2) (in-place)
    scatter_kernel<HID><<<(E * (HID / 4) + 255) / 256, 256, 0, stream>>>(
        x1, src, dst, buf3, E);
    sage_gemm<HID, HID, true, true><<<(nn + 31) / 32, 256, 0, stream>>>(
        x1, buf3, deg, Ws2, Wn2, b2, buf3, nn);

    // MLP hidden: x3 = relu(x2@Wm1 + bm1) (in-place)
    sage_gemm<HID, HID, false, true><<<(nn + 31) / 32, 256, 0, stream>>>(
        buf3, nullptr, nullptr, Wm1, nullptr, bm1, buf3, nn);

    // MLP out: out = x3@Wm2 + bm2
    sage_gemm<HID, OUT_F, false, false><<<(nn + 63) / 64, 256, 0, stream>>>(
        buf3, nullptr, nullptr, Wm2, nullptr, bm2, (float*)d_out, nn);
}

// Round 2
// 690.531 us; speedup vs baseline: 6.2790x; 6.2790x over previous
//
#include <hip/hip_runtime.h>

#define N_IN 64
#define HID 128
#define OUT_F 64

// ---------------------------------------------------------------------------
// degree count (int)
// ---------------------------------------------------------------------------
__global__ __launch_bounds__(256)
void deg_kernel(const int* __restrict__ dst, int* __restrict__ degi, int E) {
    int e = blockIdx.x * 256 + threadIdx.x;
    if (e < E) atomicAdd(&degi[dst[e]], 1);
}

// ---------------------------------------------------------------------------
// prefix-sum step 1: per-256-block exclusive scan; block totals to partials
// ---------------------------------------------------------------------------
__global__ __launch_bounds__(256)
void scan_block(const int* __restrict__ degi, int* __restrict__ offs,
                int* __restrict__ partials, int nn) {
    __shared__ int sm[256];
    int i = blockIdx.x * 256 + threadIdx.x;
    int v = (i < nn) ? degi[i] : 0;
    sm[threadIdx.x] = v;
    __syncthreads();
    for (int d = 1; d < 256; d <<= 1) {
        int t = (threadIdx.x >= d) ? sm[threadIdx.x - d] : 0;
        __syncthreads();
        sm[threadIdx.x] += t;
        __syncthreads();
    }
    if (i < nn) offs[i] = sm[threadIdx.x] - v;       // exclusive within block
    if (threadIdx.x == 255) partials[blockIdx.x] = sm[255];
}

// ---------------------------------------------------------------------------
// prefix-sum step 2: single block, exclusive scan of block totals (<=1024)
// ---------------------------------------------------------------------------
__global__ __launch_bounds__(1024)
void scan_partials(int* __restrict__ partials, int nparts) {
    __shared__ int sm[1024];
    int i = threadIdx.x;
    int v = (i < nparts) ? partials[i] : 0;
    sm[i] = v;
    __syncthreads();
    for (int d = 1; d < 1024; d <<= 1) {
        int t = (i >= d) ? sm[i - d] : 0;
        __syncthreads();
        sm[i] += t;
        __syncthreads();
    }
    if (i < nparts) partials[i] = sm[i] - v;         // exclusive
}

// ---------------------------------------------------------------------------
// prefix-sum step 3: add block offsets; init cursor; set offs[nn]=E
// ---------------------------------------------------------------------------
__global__ __launch_bounds__(256)
void finalize_offs(int* __restrict__ offs, int* __restrict__ cursor,
                   const int* __restrict__ partials, int nn, int E) {
    int i = blockIdx.x * 256 + threadIdx.x;
    if (i < nn) {
        int o = offs[i] + partials[i >> 8];
        offs[i] = o;
        cursor[i] = o;
    } else if (i == nn) {
        offs[nn] = E;
    }
}

// ---------------------------------------------------------------------------
// CSR edge placement (counting sort by dst)
// ---------------------------------------------------------------------------
__global__ __launch_bounds__(256)
void place_kernel(const int* __restrict__ src, const int* __restrict__ dst,
                  int* __restrict__ cursor, int* __restrict__ csr_src, int E) {
    int e = blockIdx.x * 256 + threadIdx.x;
    if (e < E) {
        int pos = atomicAdd(&cursor[dst[e]], 1);
        csr_src[pos] = src[e];
    }
}

// ---------------------------------------------------------------------------
// gather: agg[n][:] = sum_{j in csr[n]} x[csr_src[j]][:]
// thread = (node, float4 chunk); D/4 consecutive lanes read one row coalesced
// ---------------------------------------------------------------------------
template<int D>
__global__ __launch_bounds__(256)
void gather_kernel(const float* __restrict__ x, const int* __restrict__ csr_src,
                   const int* __restrict__ offs, float* __restrict__ agg, int nn) {
    constexpr int C = D / 4;
    int gid = blockIdx.x * 256 + threadIdx.x;
    int n = gid / C;
    if (n >= nn) return;
    int c = gid % C;
    int beg = offs[n], end = offs[n + 1];
    float4 acc = make_float4(0.f, 0.f, 0.f, 0.f);
    int j = beg;
    for (; j + 1 < end; j += 2) {
        int s0 = csr_src[j], s1 = csr_src[j + 1];
        const float4 v0 = *(const float4*)(x + (size_t)s0 * D + c * 4);
        const float4 v1 = *(const float4*)(x + (size_t)s1 * D + c * 4);
        acc.x += v0.x + v1.x; acc.y += v0.y + v1.y;
        acc.z += v0.z + v1.z; acc.w += v0.w + v1.w;
    }
    if (j < end) {
        int s = csr_src[j];
        const float4 v = *(const float4*)(x + (size_t)s * D + c * 4);
        acc.x += v.x; acc.y += v.y; acc.z += v.z; acc.w += v.w;
    }
    *(float4*)(agg + (size_t)n * D + c * 4) = acc;
}

// ---------------------------------------------------------------------------
// fused SAGE layer / MLP layer (unchanged except int degree):
//   out[n][h] = act( x[n]@Ws + (agg[n]/max(deg,1))@Wn + b )
// ---------------------------------------------------------------------------
template<int K, int H, bool NEIGH, bool RELU>
__global__ __launch_bounds__(256)
void sage_gemm(const float* __restrict__ x, const float* __restrict__ agg,
               const int* __restrict__ degi, const float* __restrict__ Ws,
               const float* __restrict__ Wn, const float* __restrict__ bias,
               float* __restrict__ out, int nn) {
    constexpr int HG   = H / 4;
    constexpr int RGS  = 256 / HG;
    constexpr int ROWS = RGS * 4;

    __shared__ float xs[ROWS][K];
    __shared__ float as_[NEIGH ? ROWS : 1][NEIGH ? K : 1];

    const int tid  = threadIdx.x;
    const int row0 = blockIdx.x * ROWS;

    constexpr int C        = K / 4;
    constexpr int TOTAL_F4 = ROWS * C;
    for (int i = tid; i < TOTAL_F4; i += 256) {
        int r = i / C, c = i % C;
        int n = row0 + r;
        float4 v = make_float4(0.f, 0.f, 0.f, 0.f);
        if (n < nn) v = *(const float4*)(x + (size_t)n * K + c * 4);
        *(float4*)&xs[r][c * 4] = v;
        if constexpr (NEIGH) {
            float4 a = make_float4(0.f, 0.f, 0.f, 0.f);
            if (n < nn) {
                a = *(const float4*)(agg + (size_t)n * K + c * 4);
                float inv = 1.0f / fmaxf((float)degi[n], 1.0f);
                a.x *= inv; a.y *= inv; a.z *= inv; a.w *= inv;
            }
            *(float4*)&as_[r][c * 4] = a;
        }
    }
    __syncthreads();

    const int rg = tid / HG;
    const int h0 = (tid % HG) * 4;
    const int r0 = rg * 4;

    float acc[4][4];
#pragma unroll
    for (int r = 0; r < 4; ++r)
#pragma unroll
        for (int j = 0; j < 4; ++j) acc[r][j] = 0.f;

#pragma unroll 4
    for (int k = 0; k < K; ++k) {
        const float4 wsv = *(const float4*)(Ws + (size_t)k * H + h0);
        float4 wnv;
        if constexpr (NEIGH) wnv = *(const float4*)(Wn + (size_t)k * H + h0);
#pragma unroll
        for (int r = 0; r < 4; ++r) {
            float xv = xs[r0 + r][k];
            acc[r][0] += xv * wsv.x;
            acc[r][1] += xv * wsv.y;
            acc[r][2] += xv * wsv.z;
            acc[r][3] += xv * wsv.w;
            if constexpr (NEIGH) {
                float av = as_[r0 + r][k];
                acc[r][0] += av * wnv.x;
                acc[r][1] += av * wnv.y;
                acc[r][2] += av * wnv.z;
                acc[r][3] += av * wnv.w;
            }
        }
    }

    const float4 bv = *(const float4*)(bias + h0);
#pragma unroll
    for (int r = 0; r < 4; ++r) {
        int n = row0 + r0 + r;
        if (n < nn) {
            float4 o;
            o.x = acc[r][0] + bv.x;
            o.y = acc[r][1] + bv.y;
            o.z = acc[r][2] + bv.z;
            o.w = acc[r][3] + bv.w;
            if constexpr (RELU) {
                o.x = fmaxf(o.x, 0.f); o.y = fmaxf(o.y, 0.f);
                o.z = fmaxf(o.z, 0.f); o.w = fmaxf(o.w, 0.f);
            }
            *(float4*)(out + (size_t)n * H + h0) = o;
        }
    }
}

// ---------------------------------------------------------------------------
extern "C" void kernel_launch(void* const* d_in, const int* in_sizes, int n_in,
                              void* d_out, int out_size, void* d_ws, size_t ws_size,
                              hipStream_t stream) {
    const float* feat = (const float*)d_in[0];
    const float* Wn1  = (const float*)d_in[1];
    const float* Ws1  = (const float*)d_in[2];
    const float* b1   = (const float*)d_in[3];
    const float* Wn2  = (const float*)d_in[4];
    const float* Ws2  = (const float*)d_in[5];
    const float* b2   = (const float*)d_in[6];
    const float* Wm1  = (const float*)d_in[7];
    const float* bm1  = (const float*)d_in[8];
    const float* Wm2  = (const float*)d_in[9];
    const float* bm2  = (const float*)d_in[10];
    const int*   src  = (const int*)d_in[11];
    const int*   dst  = (const int*)d_in[12];

    const int nn = in_sizes[0] / N_IN;    // 100000
    const int E  = in_sizes[11];          // 1600000

    // workspace layout:
    //   degi    [nn]            int
    //   offs    [nn+1]          int
    //   cursor  [nn]            int
    //   partials[1024]          int
    //   csr_src [E]             int
    //   x1      [nn*HID]        float
    //   buf3    [nn*HID]        float   (agg2 -> x2 -> x3, in-place safe)
    // agg1 lives in d_out (exactly nn*N_IN floats, dead before final GEMM).
    int* degi     = (int*)d_ws;
    int* offs     = degi + nn;
    int* cursor   = offs + (nn + 1);
    int* partials = cursor + nn;
    int* csr_src  = partials + 1024;
    float* x1     = (float*)(csr_src + E);
    float* buf3   = x1 + (size_t)nn * HID;
    float* agg1   = (float*)d_out;

    const int nparts = (nn + 255) / 256;

    hipMemsetAsync(degi, 0, (size_t)nn * sizeof(int), stream);

    // ---- build CSR (counting sort by dst) ----
    deg_kernel<<<(E + 255) / 256, 256, 0, stream>>>(dst, degi, E);
    scan_block<<<nparts, 256, 0, stream>>>(degi, offs, partials, nn);
    scan_partials<<<1, 1024, 0, stream>>>(partials, nparts);
    finalize_offs<<<(nn + 256) / 256, 256, 0, stream>>>(offs, cursor, partials, nn, E);
    place_kernel<<<(E + 255) / 256, 256, 0, stream>>>(src, dst, cursor, csr_src, E);

    // ---- layer 1 ----
    gather_kernel<N_IN><<<((size_t)nn * (N_IN / 4) + 255) / 256, 256, 0, stream>>>(
        feat, csr_src, offs, agg1, nn);
    sage_gemm<N_IN, HID, true, true><<<(nn + 31) / 32, 256, 0, stream>>>(
        feat, agg1, degi, Ws1, Wn1, b1, x1, nn);

    // ---- layer 2 ----
    gather_kernel<HID><<<((size_t)nn * (HID / 4) + 255) / 256, 256, 0, stream>>>(
        x1, csr_src, offs, buf3, nn);
    sage_gemm<HID, HID, true, true><<<(nn + 31) / 32, 256, 0, stream>>>(
        x1, buf3, degi, Ws2, Wn2, b2, buf3, nn);

    // ---- MLP ----
    sage_gemm<HID, HID, false, true><<<(nn + 31) / 32, 256, 0, stream>>>(
        buf3, nullptr, nullptr, Wm1, nullptr, bm1, buf3, nn);
    sage_gemm<HID, OUT_F, false, false><<<(nn + 63) / 64, 256, 0, stream>>>(
        buf3, nullptr, nullptr, Wm2, nullptr, bm2, (float*)d_out, nn);
}

// Round 3
// 604.343 us; speedup vs baseline: 7.1745x; 1.1426x over previous
//
#include <hip/hip_runtime.h>

#define N_IN 64
#define HID 128
#define OUT_F 64

typedef unsigned short ushort_t;
typedef ushort_t us8 __attribute__((ext_vector_type(8)));
typedef ushort_t us4 __attribute__((ext_vector_type(4)));
typedef float f32x4 __attribute__((ext_vector_type(4)));

__device__ inline ushort_t f2bf(float f) {          // round-to-nearest-even
    unsigned u = __float_as_uint(f);
    u = u + 0x7fffu + ((u >> 16) & 1u);
    return (ushort_t)(u >> 16);
}
__device__ inline float bf2f(ushort_t b) {
    return __uint_as_float((unsigned)b << 16);
}

// ---------------------------------------------------------------------------
// fp32 -> bf16 row conversion (16B out per thread)
// ---------------------------------------------------------------------------
__global__ __launch_bounds__(256)
void cvt_bf16(const float* __restrict__ in, ushort_t* __restrict__ out, int n8) {
    int i = blockIdx.x * 256 + threadIdx.x;
    if (i >= n8) return;
    f32x4 a = ((const f32x4*)in)[2 * i];
    f32x4 b = ((const f32x4*)in)[2 * i + 1];
    us8 v;
#pragma unroll
    for (int t = 0; t < 4; ++t) v[t] = f2bf(a[t]);
#pragma unroll
    for (int t = 0; t < 4; ++t) v[4 + t] = f2bf(b[t]);
    ((us8*)out)[i] = v;
}

// ---------------------------------------------------------------------------
// degree count (int)
// ---------------------------------------------------------------------------
__global__ __launch_bounds__(256)
void deg_kernel(const int* __restrict__ dst, int* __restrict__ degi, int E) {
    int e = blockIdx.x * 256 + threadIdx.x;
    if (e < E) atomicAdd(&degi[dst[e]], 1);
}

// ---------------------------------------------------------------------------
// prefix-sum step 1: per-256-block exclusive scan
// ---------------------------------------------------------------------------
__global__ __launch_bounds__(256)
void scan_block(const int* __restrict__ degi, int* __restrict__ offs,
                int* __restrict__ partials, int nn) {
    __shared__ int sm[256];
    int i = blockIdx.x * 256 + threadIdx.x;
    int v = (i < nn) ? degi[i] : 0;
    sm[threadIdx.x] = v;
    __syncthreads();
    for (int d = 1; d < 256; d <<= 1) {
        int t = (threadIdx.x >= d) ? sm[threadIdx.x - d] : 0;
        __syncthreads();
        sm[threadIdx.x] += t;
        __syncthreads();
    }
    if (i < nn) offs[i] = sm[threadIdx.x] - v;
    if (threadIdx.x == 255) partials[blockIdx.x] = sm[255];
}

// ---------------------------------------------------------------------------
// prefix-sum step 2: single block over block totals (<=1024)
// ---------------------------------------------------------------------------
__global__ __launch_bounds__(1024)
void scan_partials(int* __restrict__ partials, int nparts) {
    __shared__ int sm[1024];
    int i = threadIdx.x;
    int v = (i < nparts) ? partials[i] : 0;
    sm[i] = v;
    __syncthreads();
    for (int d = 1; d < 1024; d <<= 1) {
        int t = (i >= d) ? sm[i - d] : 0;
        __syncthreads();
        sm[i] += t;
        __syncthreads();
    }
    if (i < nparts) partials[i] = sm[i] - v;
}

// ---------------------------------------------------------------------------
// prefix-sum step 3: global offsets, cursor init, inv-degree, offs[nn]=E
// ---------------------------------------------------------------------------
__global__ __launch_bounds__(256)
void finalize_offs(int* __restrict__ offs, int* __restrict__ cursor,
                   float* __restrict__ invd, const int* __restrict__ partials,
                   const int* __restrict__ degi, int nn, int E) {
    int i = blockIdx.x * 256 + threadIdx.x;
    if (i < nn) {
        int o = offs[i] + partials[i >> 8];
        offs[i] = o;
        cursor[i] = o;
        invd[i] = 1.0f / fmaxf((float)degi[i], 1.0f);
    } else if (i == nn) {
        offs[nn] = E;
    }
}

// ---------------------------------------------------------------------------
// CSR edge placement (counting sort by dst)
// ---------------------------------------------------------------------------
__global__ __launch_bounds__(256)
void place_kernel(const int* __restrict__ src, const int* __restrict__ dst,
                  int* __restrict__ cursor, int* __restrict__ csr_src, int E) {
    int e = blockIdx.x * 256 + threadIdx.x;
    if (e < E) {
        int pos = atomicAdd(&cursor[dst[e]], 1);
        csr_src[pos] = src[e];
    }
}

// ---------------------------------------------------------------------------
// gather (bf16 rows, fp32 accumulate, mean folded in):
//   agg[n][:] = invd[n] * sum_{j} xb[csr_src[j]][:]
// thread = (node, 8-col chunk); D/8 lanes read one 2B*D row coalesced (16B/lane)
// ---------------------------------------------------------------------------
template<int D>
__global__ __launch_bounds__(256)
void gather_bf16(const ushort_t* __restrict__ xb, const int* __restrict__ csr_src,
                 const int* __restrict__ offs, const float* __restrict__ invd,
                 float* __restrict__ agg, int nn) {
    constexpr int C = D / 8;
    int gid = blockIdx.x * 256 + threadIdx.x;
    int n = gid / C;
    if (n >= nn) return;
    int c = gid % C;
    int beg = offs[n], end = offs[n + 1];
    float acc[8] = {0.f, 0.f, 0.f, 0.f, 0.f, 0.f, 0.f, 0.f};
    int j = beg;
    for (; j + 1 < end; j += 2) {
        int s0 = csr_src[j], s1 = csr_src[j + 1];
        us8 v0 = *(const us8*)(xb + (size_t)s0 * D + c * 8);
        us8 v1 = *(const us8*)(xb + (size_t)s1 * D + c * 8);
#pragma unroll
        for (int t = 0; t < 8; ++t) acc[t] += bf2f(v0[t]) + bf2f(v1[t]);
    }
    if (j < end) {
        int s = csr_src[j];
        us8 v = *(const us8*)(xb + (size_t)s * D + c * 8);
#pragma unroll
        for (int t = 0; t < 8; ++t) acc[t] += bf2f(v[t]);
    }
    float iv = invd[n];
    f32x4 o0, o1;
#pragma unroll
    for (int t = 0; t < 4; ++t) { o0[t] = acc[t] * iv; o1[t] = acc[4 + t] * iv; }
    *(f32x4*)(agg + (size_t)n * D + c * 8) = o0;
    *(f32x4*)(agg + (size_t)n * D + c * 8 + 4) = o1;
}

// ---------------------------------------------------------------------------
// fused layer:  out[n][h] = act( x[n]@Ws + agg[n]@Wn + b )   (agg already mean)
// x may be bf16 (XBF) and out may be bf16 (OBF). In-place out==agg safe.
// ---------------------------------------------------------------------------
template<int K, int H, bool NEIGH, bool RELU, bool XBF, bool OBF>
__global__ __launch_bounds__(256)
void sage_gemm(const void* __restrict__ xin, const float* __restrict__ agg,
               const float* __restrict__ Ws, const float* __restrict__ Wn,
               const float* __restrict__ bias, void* __restrict__ out, int nn) {
    constexpr int HG   = H / 4;
    constexpr int RGS  = 256 / HG;
    constexpr int ROWS = RGS * 4;

    __shared__ float xs[ROWS][K];
    __shared__ float as_[NEIGH ? ROWS : 1][NEIGH ? K : 1];

    const int tid  = threadIdx.x;
    const int row0 = blockIdx.x * ROWS;

    // ---- stage x ----
    if constexpr (XBF) {
        const ushort_t* xb = (const ushort_t*)xin;
        constexpr int CH = K / 8;
        for (int i = tid; i < ROWS * CH; i += 256) {
            int r = i / CH, c = i % CH, n = row0 + r;
            if (n < nn) {
                us8 v = *(const us8*)(xb + (size_t)n * K + c * 8);
#pragma unroll
                for (int t = 0; t < 8; ++t) xs[r][c * 8 + t] = bf2f(v[t]);
            } else {
#pragma unroll
                for (int t = 0; t < 8; ++t) xs[r][c * 8 + t] = 0.f;
            }
        }
    } else {
        const float* xf = (const float*)xin;
        constexpr int CH = K / 4;
        for (int i = tid; i < ROWS * CH; i += 256) {
            int r = i / CH, c = i % CH, n = row0 + r;
            f32x4 v = {0.f, 0.f, 0.f, 0.f};
            if (n < nn) v = *(const f32x4*)(xf + (size_t)n * K + c * 4);
            *(f32x4*)&xs[r][c * 4] = v;
        }
    }
    // ---- stage agg ----
    if constexpr (NEIGH) {
        constexpr int CH = K / 4;
        for (int i = tid; i < ROWS * CH; i += 256) {
            int r = i / CH, c = i % CH, n = row0 + r;
            f32x4 a = {0.f, 0.f, 0.f, 0.f};
            if (n < nn) a = *(const f32x4*)(agg + (size_t)n * K + c * 4);
            *(f32x4*)&as_[r][c * 4] = a;
        }
    }
    __syncthreads();

    const int rg = tid / HG;
    const int h0 = (tid % HG) * 4;
    const int r0 = rg * 4;

    float acc[4][4];
#pragma unroll
    for (int r = 0; r < 4; ++r)
#pragma unroll
        for (int j = 0; j < 4; ++j) acc[r][j] = 0.f;

#pragma unroll 2
    for (int k0 = 0; k0 < K; k0 += 4) {
        f32x4 xr[4], ar[4];
#pragma unroll
        for (int r = 0; r < 4; ++r) xr[r] = *(const f32x4*)&xs[r0 + r][k0];
        if constexpr (NEIGH) {
#pragma unroll
            for (int r = 0; r < 4; ++r) ar[r] = *(const f32x4*)&as_[r0 + r][k0];
        }
#pragma unroll
        for (int kk = 0; kk < 4; ++kk) {
            const f32x4 wsv = *(const f32x4*)(Ws + (size_t)(k0 + kk) * H + h0);
            f32x4 wnv;
            if constexpr (NEIGH) wnv = *(const f32x4*)(Wn + (size_t)(k0 + kk) * H + h0);
#pragma unroll
            for (int r = 0; r < 4; ++r) {
                const float xv = xr[r][kk];
#pragma unroll
                for (int j = 0; j < 4; ++j) acc[r][j] += xv * wsv[j];
                if constexpr (NEIGH) {
                    const float av = ar[r][kk];
#pragma unroll
                    for (int j = 0; j < 4; ++j) acc[r][j] += av * wnv[j];
                }
            }
        }
    }

    const f32x4 bv = *(const f32x4*)(bias + h0);
#pragma unroll
    for (int r = 0; r < 4; ++r) {
        int n = row0 + r0 + r;
        if (n < nn) {
            f32x4 o;
#pragma unroll
            for (int j = 0; j < 4; ++j) {
                float v = acc[r][j] + bv[j];
                if constexpr (RELU) v = fmaxf(v, 0.f);
                o[j] = v;
            }
            if constexpr (OBF) {
                us4 ov;
#pragma unroll
                for (int j = 0; j < 4; ++j) ov[j] = f2bf(o[j]);
                *(us4*)((ushort_t*)out + (size_t)n * H + h0) = ov;
            } else {
                *(f32x4*)((float*)out + (size_t)n * H + h0) = o;
            }
        }
    }
}

// ---------------------------------------------------------------------------
extern "C" void kernel_launch(void* const* d_in, const int* in_sizes, int n_in,
                              void* d_out, int out_size, void* d_ws, size_t ws_size,
                              hipStream_t stream) {
    const float* feat = (const float*)d_in[0];
    const float* Wn1  = (const float*)d_in[1];
    const float* Ws1  = (const float*)d_in[2];
    const float* b1   = (const float*)d_in[3];
    const float* Wn2  = (const float*)d_in[4];
    const float* Ws2  = (const float*)d_in[5];
    const float* b2   = (const float*)d_in[6];
    const float* Wm1  = (const float*)d_in[7];
    const float* bm1  = (const float*)d_in[8];
    const float* Wm2  = (const float*)d_in[9];
    const float* bm2  = (const float*)d_in[10];
    const int*   src  = (const int*)d_in[11];
    const int*   dst  = (const int*)d_in[12];

    const int nn = in_sizes[0] / N_IN;    // 100000
    const int E  = in_sizes[11];          // 1600000

    // workspace layout:
    //   degi[nn] offs[nn+1] cursor[nn] partials[1024] int; invd[nn] float;
    //   csr_src[E] int; x1b[nn*HID] bf16; buf3[nn*HID] float
    //   featb (bf16, nn*N_IN) aliases the START of buf3 (dead before gather2)
    //   agg1 (fp32, nn*N_IN) lives in d_out (dead before final GEMM)
    int*   degi     = (int*)d_ws;
    int*   offs     = degi + nn;
    int*   cursor   = offs + (nn + 1);
    int*   partials = cursor + nn;
    float* invd     = (float*)(partials + 1024);
    int*   csr_src  = (int*)(invd + nn);
    ushort_t* x1b   = (ushort_t*)(csr_src + E);
    float* buf3     = (float*)(x1b + (size_t)nn * HID);
    ushort_t* featb = (ushort_t*)buf3;
    float* agg1     = (float*)d_out;

    const int nparts = (nn + 255) / 256;

    hipMemsetAsync(degi, 0, (size_t)nn * sizeof(int), stream);

    // ---- bf16 copies + CSR build ----
    cvt_bf16<<<((size_t)nn * (N_IN / 8) + 255) / 256, 256, 0, stream>>>(
        feat, featb, nn * (N_IN / 8));
    deg_kernel<<<(E + 255) / 256, 256, 0, stream>>>(dst, degi, E);
    scan_block<<<nparts, 256, 0, stream>>>(degi, offs, partials, nn);
    scan_partials<<<1, 1024, 0, stream>>>(partials, nparts);
    finalize_offs<<<(nn + 256) / 256, 256, 0, stream>>>(offs, cursor, invd, partials, degi, nn, E);
    place_kernel<<<(E + 255) / 256, 256, 0, stream>>>(src, dst, cursor, csr_src, E);

    // ---- layer 1: agg1 = mean-gather(featb); x1b = bf16(relu(feat@Ws1 + agg1@Wn1 + b1)) ----
    gather_bf16<N_IN><<<((size_t)nn * (N_IN / 8) + 255) / 256, 256, 0, stream>>>(
        featb, csr_src, offs, invd, agg1, nn);
    sage_gemm<N_IN, HID, true, true, false, true><<<(nn + 31) / 32, 256, 0, stream>>>(
        feat, agg1, Ws1, Wn1, b1, x1b, nn);

    // ---- layer 2: buf3 = mean-gather(x1b); x2 = relu(x1b@Ws2 + buf3@Wn2 + b2) in-place ----
    gather_bf16<HID><<<((size_t)nn * (HID / 8) + 255) / 256, 256, 0, stream>>>(
        x1b, csr_src, offs, invd, buf3, nn);
    sage_gemm<HID, HID, true, true, true, false><<<(nn + 31) / 32, 256, 0, stream>>>(
        x1b, buf3, Ws2, Wn2, b2, buf3, nn);

    // ---- MLP ----
    sage_gemm<HID, HID, false, true, false, false><<<(nn + 31) / 32, 256, 0, stream>>>(
        buf3, nullptr, Wm1, nullptr, bm1, buf3, nn);
    sage_gemm<HID, OUT_F, false, false, false, false><<<(nn + 63) / 64, 256, 0, stream>>>(
        buf3, nullptr, Wm2, nullptr, bm2, (float*)d_out, nn);
}

// Round 4
// 488.492 us; speedup vs baseline: 8.8760x; 1.2372x over previous
//
#include <hip/hip_runtime.h>

#define N_IN 64
#define HID 128
#define OUT_F 64

typedef unsigned short ushort_t;
typedef ushort_t us8 __attribute__((ext_vector_type(8)));
typedef short    s16x8 __attribute__((ext_vector_type(8)));
typedef float    f32x4 __attribute__((ext_vector_type(4)));

__device__ inline ushort_t f2bf(float f) {          // round-to-nearest-even
    unsigned u = __float_as_uint(f);
    u = u + 0x7fffu + ((u >> 16) & 1u);
    return (ushort_t)(u >> 16);
}
__device__ inline float bf2f(ushort_t b) {
    return __uint_as_float((unsigned)b << 16);
}

// ---------------------------------------------------------------------------
// fp32 -> bf16 row conversion (16B out per thread)
// ---------------------------------------------------------------------------
__global__ __launch_bounds__(256)
void cvt_bf16(const float* __restrict__ in, ushort_t* __restrict__ out, int n8) {
    int i = blockIdx.x * 256 + threadIdx.x;
    if (i >= n8) return;
    f32x4 a = ((const f32x4*)in)[2 * i];
    f32x4 b = ((const f32x4*)in)[2 * i + 1];
    us8 v;
#pragma unroll
    for (int t = 0; t < 4; ++t) v[t] = f2bf(a[t]);
#pragma unroll
    for (int t = 0; t < 4; ++t) v[4 + t] = f2bf(b[t]);
    ((us8*)out)[i] = v;
}

// ---------------------------------------------------------------------------
// weight convert + transpose: WT[h][k] = bf16(W[k][h]); i over H*K
// ---------------------------------------------------------------------------
__global__ __launch_bounds__(256)
void cvtT(const float* __restrict__ W, ushort_t* __restrict__ WT, int K, int H) {
    int i = blockIdx.x * 256 + threadIdx.x;
    if (i >= H * K) return;
    int h = i / K, k = i % K;
    WT[i] = f2bf(W[(size_t)k * H + h]);
}

// ---------------------------------------------------------------------------
// degree + rank: rank[e] = old count (coalesced write); degi counts
// ---------------------------------------------------------------------------
__global__ __launch_bounds__(256)
void deg_rank(const int* __restrict__ dst, int* __restrict__ degi,
              int* __restrict__ rank, int E) {
    int e = blockIdx.x * 256 + threadIdx.x;
    if (e < E) {
        int r = atomicAdd(&degi[dst[e]], 1);
        __builtin_nontemporal_store(r, &rank[e]);
    }
}

// ---------------------------------------------------------------------------
// prefix-sum step 1: per-256-block exclusive scan
// ---------------------------------------------------------------------------
__global__ __launch_bounds__(256)
void scan_block(const int* __restrict__ degi, int* __restrict__ offs,
                int* __restrict__ partials, int nn) {
    __shared__ int sm[256];
    int i = blockIdx.x * 256 + threadIdx.x;
    int v = (i < nn) ? degi[i] : 0;
    sm[threadIdx.x] = v;
    __syncthreads();
    for (int d = 1; d < 256; d <<= 1) {
        int t = (threadIdx.x >= d) ? sm[threadIdx.x - d] : 0;
        __syncthreads();
        sm[threadIdx.x] += t;
        __syncthreads();
    }
    if (i < nn) offs[i] = sm[threadIdx.x] - v;
    if (threadIdx.x == 255) partials[blockIdx.x] = sm[255];
}

__global__ __launch_bounds__(1024)
void scan_partials(int* __restrict__ partials, int nparts) {
    __shared__ int sm[1024];
    int i = threadIdx.x;
    int v = (i < nparts) ? partials[i] : 0;
    sm[i] = v;
    __syncthreads();
    for (int d = 1; d < 1024; d <<= 1) {
        int t = (i >= d) ? sm[i - d] : 0;
        __syncthreads();
        sm[i] += t;
        __syncthreads();
    }
    if (i < nparts) partials[i] = sm[i] - v;
}

__global__ __launch_bounds__(256)
void finalize_offs(int* __restrict__ offs, float* __restrict__ invd,
                   const int* __restrict__ partials, const int* __restrict__ degi,
                   int nn, int E) {
    int i = blockIdx.x * 256 + threadIdx.x;
    if (i < nn) {
        offs[i] = offs[i] + partials[i >> 8];
        invd[i] = 1.0f / fmaxf((float)degi[i], 1.0f);
    } else if (i == nn) {
        offs[nn] = E;
    }
}

// ---------------------------------------------------------------------------
// CSR edge placement: atomic-free, nontemporal scatter store
// ---------------------------------------------------------------------------
__global__ __launch_bounds__(256)
void place2(const int* __restrict__ src, const int* __restrict__ dst,
            const int* __restrict__ rank, const int* __restrict__ offs,
            int* __restrict__ csr_src, int E) {
    int e = blockIdx.x * 256 + threadIdx.x;
    if (e < E) {
        int pos = offs[dst[e]] + rank[e];
        __builtin_nontemporal_store(src[e], &csr_src[pos]);
    }
}

// ---------------------------------------------------------------------------
// gather (bf16 rows in, fp32 accum, mean folded, bf16 out):
//   agg[n][:] = bf16( invd[n] * sum_j xb[csr_src[j]][:] )
// ---------------------------------------------------------------------------
template<int D>
__global__ __launch_bounds__(256)
void gather_bf16(const ushort_t* __restrict__ xb, const int* __restrict__ csr_src,
                 const int* __restrict__ offs, const float* __restrict__ invd,
                 ushort_t* __restrict__ aggb, int nn) {
    constexpr int C = D / 8;
    int gid = blockIdx.x * 256 + threadIdx.x;
    int n = gid / C;
    if (n >= nn) return;
    int c = gid % C;
    int beg = offs[n], end = offs[n + 1];
    float acc[8] = {0.f, 0.f, 0.f, 0.f, 0.f, 0.f, 0.f, 0.f};
    int j = beg;
    for (; j + 1 < end; j += 2) {
        int s0 = csr_src[j], s1 = csr_src[j + 1];
        us8 v0 = *(const us8*)(xb + (size_t)s0 * D + c * 8);
        us8 v1 = *(const us8*)(xb + (size_t)s1 * D + c * 8);
#pragma unroll
        for (int t = 0; t < 8; ++t) acc[t] += bf2f(v0[t]) + bf2f(v1[t]);
    }
    if (j < end) {
        int s = csr_src[j];
        us8 v = *(const us8*)(xb + (size_t)s * D + c * 8);
#pragma unroll
        for (int t = 0; t < 8; ++t) acc[t] += bf2f(v[t]);
    }
    float iv = invd[n];
    us8 ov;
#pragma unroll
    for (int t = 0; t < 8; ++t) ov[t] = f2bf(acc[t] * iv);
    *(us8*)(aggb + (size_t)n * D + c * 8) = ov;
}

// ---------------------------------------------------------------------------
// MFMA SAGE layer: out[n][0..127] = relu( xb[n]@Ws + gb[n]@Wn + b )
// bf16 inputs, fp32 accum via v_mfma_f32_16x16x32_bf16.
// Block = 256 thr = 4 waves, 64 nodes/block; wave w owns 16 nodes x 128 h.
// A-frag: row=lane&15, k=8*(lane>>4)+e (contiguous b128 from XOR-swizzled LDS).
// B-frag: col=lane&15, k=8*(lane>>4)+e (contiguous b128 from WT[h][k] global).
// D: col(h)=lane&15, row(node)=4*(lane>>4)+reg.
// ---------------------------------------------------------------------------
template<int K, bool OBF>
__global__ __launch_bounds__(256)
void mfma_layer(const ushort_t* __restrict__ xb, const ushort_t* __restrict__ gb,
                const ushort_t* __restrict__ wsT, const ushort_t* __restrict__ wnT,
                const float* __restrict__ bias, void* __restrict__ out, int nn) {
    constexpr int CH = K / 8;                 // 16B chunks per row
    __shared__ us8 xs[64][CH];
    __shared__ us8 gs[64][CH];

    const int tid  = threadIdx.x;
    const int row0 = blockIdx.x * 64;

    // ---- stage 64 rows of x and agg, XOR-swizzled (c ^= r&7) ----
    for (int i = tid; i < 64 * CH; i += 256) {
        int r = i / CH, c = i % CH;
        int n = row0 + r;
        us8 vx = {0, 0, 0, 0, 0, 0, 0, 0};
        us8 vg = {0, 0, 0, 0, 0, 0, 0, 0};
        if (n < nn) {
            vx = *(const us8*)(xb + (size_t)n * K + c * 8);
            vg = *(const us8*)(gb + (size_t)n * K + c * 8);
        }
        int cs = c ^ (r & 7);
        xs[r][cs] = vx;
        gs[r][cs] = vg;
    }
    __syncthreads();

    const int lane = tid & 63;
    const int w    = tid >> 6;
    const int lr   = lane & 15;               // A-row / B-col / D-col index
    const int lk   = lane >> 4;               // k-group
    const int R    = w * 16 + lr;             // LDS row for A-frags

    f32x4 acc[8];
#pragma unroll
    for (int t = 0; t < 8; ++t) acc[t] = {0.f, 0.f, 0.f, 0.f};

#pragma unroll
    for (int ks = 0; ks < K / 32; ++ks) {
        int c = ks * 4 + lk;
        int cs = c ^ (R & 7);
        s16x8 ax = (s16x8)xs[R][cs];
        s16x8 ag = (s16x8)gs[R][cs];
        const size_t wko = (size_t)(ks * 32 + lk * 8);
#pragma unroll
        for (int t = 0; t < 8; ++t) {
            const size_t hrow = (size_t)(t * 16 + lr) * K;
            s16x8 bs = *(const s16x8*)(wsT + hrow + wko);
            s16x8 bn = *(const s16x8*)(wnT + hrow + wko);
            acc[t] = __builtin_amdgcn_mfma_f32_16x16x32_bf16(ax, bs, acc[t], 0, 0, 0);
            acc[t] = __builtin_amdgcn_mfma_f32_16x16x32_bf16(ag, bn, acc[t], 0, 0, 0);
        }
    }

    // ---- epilogue: bias + relu + store ----
#pragma unroll
    for (int t = 0; t < 8; ++t) {
        float bv = bias[t * 16 + lr];
        int h = t * 16 + lr;
#pragma unroll
        for (int j = 0; j < 4; ++j) {
            int n = row0 + w * 16 + lk * 4 + j;
            if (n < nn) {
                float v = fmaxf(acc[t][j] + bv, 0.f);
                if constexpr (OBF)
                    ((ushort_t*)out)[(size_t)n * HID + h] = f2bf(v);
                else
                    ((float*)out)[(size_t)n * HID + h] = v;
            }
        }
    }
}

// ---------------------------------------------------------------------------
// fp32 vector MLP layer: out[n][h] = act( x[n]@W + b )  (in-place safe)
// ---------------------------------------------------------------------------
template<int K, int H, bool RELU>
__global__ __launch_bounds__(256)
void mlp_gemm(const float* __restrict__ x, const float* __restrict__ W,
              const float* __restrict__ bias, float* __restrict__ out, int nn) {
    constexpr int HG   = H / 4;
    constexpr int RGS  = 256 / HG;
    constexpr int ROWS = RGS * 4;

    __shared__ float xs[ROWS][K];

    const int tid  = threadIdx.x;
    const int row0 = blockIdx.x * ROWS;

    constexpr int CHN = K / 4;
    for (int i = tid; i < ROWS * CHN; i += 256) {
        int r = i / CHN, c = i % CHN, n = row0 + r;
        f32x4 v = {0.f, 0.f, 0.f, 0.f};
        if (n < nn) v = *(const f32x4*)(x + (size_t)n * K + c * 4);
        *(f32x4*)&xs[r][c * 4] = v;
    }
    __syncthreads();

    const int rg = tid / HG;
    const int h0 = (tid % HG) * 4;
    const int r0 = rg * 4;

    float acc[4][4];
#pragma unroll
    for (int r = 0; r < 4; ++r)
#pragma unroll
        for (int j = 0; j < 4; ++j) acc[r][j] = 0.f;

#pragma unroll 2
    for (int k0 = 0; k0 < K; k0 += 4) {
        f32x4 xr[4];
#pragma unroll
        for (int r = 0; r < 4; ++r) xr[r] = *(const f32x4*)&xs[r0 + r][k0];
#pragma unroll
        for (int kk = 0; kk < 4; ++kk) {
            const f32x4 wv = *(const f32x4*)(W + (size_t)(k0 + kk) * H + h0);
#pragma unroll
            for (int r = 0; r < 4; ++r) {
                const float xv = xr[r][kk];
#pragma unroll
                for (int j = 0; j < 4; ++j) acc[r][j] += xv * wv[j];
            }
        }
    }

    const f32x4 bv = *(const f32x4*)(bias + h0);
#pragma unroll
    for (int r = 0; r < 4; ++r) {
        int n = row0 + r0 + r;
        if (n < nn) {
            f32x4 o;
#pragma unroll
            for (int j = 0; j < 4; ++j) {
                float v = acc[r][j] + bv[j];
                if constexpr (RELU) v = fmaxf(v, 0.f);
                o[j] = v;
            }
            *(f32x4*)(out + (size_t)n * H + h0) = o;
        }
    }
}

// ---------------------------------------------------------------------------
extern "C" void kernel_launch(void* const* d_in, const int* in_sizes, int n_in,
                              void* d_out, int out_size, void* d_ws, size_t ws_size,
                              hipStream_t stream) {
    const float* feat = (const float*)d_in[0];
    const float* Wn1  = (const float*)d_in[1];
    const float* Ws1  = (const float*)d_in[2];
    const float* b1   = (const float*)d_in[3];
    const float* Wn2  = (const float*)d_in[4];
    const float* Ws2  = (const float*)d_in[5];
    const float* b2   = (const float*)d_in[6];
    const float* Wm1  = (const float*)d_in[7];
    const float* bm1  = (const float*)d_in[8];
    const float* Wm2  = (const float*)d_in[9];
    const float* bm2  = (const float*)d_in[10];
    const int*   src  = (const int*)d_in[11];
    const int*   dst  = (const int*)d_in[12];

    const int nn = in_sizes[0] / N_IN;    // 100000
    const int E  = in_sizes[11];          // 1600000

    // ---- workspace carve-up (64B-aligned segments) ----
    char* p = (char*)d_ws;
    auto alloc = [&](size_t bytes) { void* q = p; p += (bytes + 63) & ~(size_t)63; return q; };
    int*      degi     = (int*)alloc((size_t)nn * 4);
    int*      offs     = (int*)alloc((size_t)(nn + 1) * 4);
    int*      partials = (int*)alloc(1024 * 4);
    float*    invd     = (float*)alloc((size_t)nn * 4);
    int*      rank     = (int*)alloc((size_t)E * 4);
    int*      csr_src  = (int*)alloc((size_t)E * 4);
    ushort_t* wsT1     = (ushort_t*)alloc((size_t)N_IN * HID * 2);
    ushort_t* wnT1     = (ushort_t*)alloc((size_t)N_IN * HID * 2);
    ushort_t* wsT2     = (ushort_t*)alloc((size_t)HID * HID * 2);
    ushort_t* wnT2     = (ushort_t*)alloc((size_t)HID * HID * 2);
    ushort_t* x1b      = (ushort_t*)alloc((size_t)nn * HID * 2);
    ushort_t* agg2b    = (ushort_t*)alloc((size_t)nn * HID * 2);
    float*    buf3     = (float*)alloc((size_t)nn * HID * 4);
    ushort_t* featb    = (ushort_t*)buf3;            // dead before buf3 written
    ushort_t* agg1b    = (ushort_t*)d_out;           // dead before final GEMM

    const int nparts = (nn + 255) / 256;

    hipMemsetAsync(degi, 0, (size_t)nn * sizeof(int), stream);

    // ---- bf16 conversions ----
    cvt_bf16<<<((size_t)nn * (N_IN / 8) + 255) / 256, 256, 0, stream>>>(
        feat, featb, nn * (N_IN / 8));
    cvtT<<<(N_IN * HID + 255) / 256, 256, 0, stream>>>(Ws1, wsT1, N_IN, HID);
    cvtT<<<(N_IN * HID + 255) / 256, 256, 0, stream>>>(Wn1, wnT1, N_IN, HID);
    cvtT<<<(HID * HID + 255) / 256, 256, 0, stream>>>(Ws2, wsT2, HID, HID);
    cvtT<<<(HID * HID + 255) / 256, 256, 0, stream>>>(Wn2, wnT2, HID, HID);

    // ---- CSR build ----
    deg_rank<<<(E + 255) / 256, 256, 0, stream>>>(dst, degi, rank, E);
    scan_block<<<nparts, 256, 0, stream>>>(degi, offs, partials, nn);
    scan_partials<<<1, 1024, 0, stream>>>(partials, nparts);
    finalize_offs<<<(nn + 256) / 256, 256, 0, stream>>>(offs, invd, partials, degi, nn, E);
    place2<<<(E + 255) / 256, 256, 0, stream>>>(src, dst, rank, offs, csr_src, E);

    // ---- layer 1 ----
    gather_bf16<N_IN><<<((size_t)nn * (N_IN / 8) + 255) / 256, 256, 0, stream>>>(
        featb, csr_src, offs, invd, agg1b, nn);
    mfma_layer<N_IN, true><<<(nn + 63) / 64, 256, 0, stream>>>(
        featb, agg1b, wsT1, wnT1, b1, x1b, nn);

    // ---- layer 2 ----
    gather_bf16<HID><<<((size_t)nn * (HID / 8) + 255) / 256, 256, 0, stream>>>(
        x1b, csr_src, offs, invd, agg2b, nn);
    mfma_layer<HID, false><<<(nn + 63) / 64, 256, 0, stream>>>(
        x1b, agg2b, wsT2, wnT2, b2, buf3, nn);

    // ---- MLP (fp32 vector) ----
    mlp_gemm<HID, HID, true><<<(nn + 31) / 32, 256, 0, stream>>>(
        buf3, Wm1, bm1, buf3, nn);
    mlp_gemm<HID, OUT_F, false><<<(nn + 63) / 64, 256, 0, stream>>>(
        buf3, Wm2, bm2, (float*)d_out, nn);
}